// Round 12
// baseline (215.251 us; speedup 1.0000x reference)
//
#include <hip/hip_runtime.h>

// ---- problem geometry ----
#define M_TOTAL 16384          // B*L
#define N_DIM   1024           // D
#define K_DIM   1024
#define L_SEQ   4096
#define B_SZ    4
#define D_DIM   1024
#define CH      64             // scan chunk length
#define NCHUNK  (L_SEQ / CH)   // 64
#define NCHAN   (B_SZ * D_DIM) // 4096

// ---- GEMM tile: 256x256, BK=64 (2 K-halves), 8 waves 2Mx4N ----
#define BK2 64
#define NT2 (K_DIM / BK2)      // 16
#define GTPB 512

typedef __attribute__((ext_vector_type(8))) short v8s;
typedef __attribute__((ext_vector_type(4))) float f32x4;

#define SB0()   __builtin_amdgcn_sched_barrier(0)
#define BAR()   __builtin_amdgcn_s_barrier()
#define WAITL0() do { asm volatile("s_waitcnt lgkmcnt(0)" ::: "memory"); SB0(); } while (0)
#define WAITV6() do { asm volatile("s_waitcnt vmcnt(6)"   ::: "memory"); SB0(); } while (0)
#define WAITV4() do { asm volatile("s_waitcnt vmcnt(4)"   ::: "memory"); SB0(); } while (0)
#define WAITV0() do { asm volatile("s_waitcnt vmcnt(0)"   ::: "memory"); SB0(); } while (0)
#define AS1 __attribute__((address_space(1)))
#define AS3 __attribute__((address_space(3)))

__device__ __forceinline__ ushort f2b(float f) {
  uint u = __float_as_uint(f);
  u += 0x7FFFu + ((u >> 16) & 1u);   // RNE (finite inputs)
  return (ushort)(u >> 16);
}
__device__ __forceinline__ float b2f(ushort u) {
  return __uint_as_float(((uint)u) << 16);
}

__global__ void cast_f32_bf16(const float* __restrict__ src, ushort* __restrict__ dst, int n4) {
  int i = blockIdx.x * blockDim.x + threadIdx.x;
  if (i >= n4) return;
  float4 v = reinterpret_cast<const float4*>(src)[i];
  ushort4 o = make_ushort4(f2b(v.x), f2b(v.y), f2b(v.z), f2b(v.w));
  reinterpret_cast<ushort4*>(dst)[i] = o;
}

__global__ void cast_w3(const float* __restrict__ s0, const float* __restrict__ s1,
                        const float* __restrict__ s2,
                        ushort* __restrict__ o0, ushort* __restrict__ o1, ushort* __restrict__ o2) {
  int i = blockIdx.x * blockDim.x + threadIdx.x;
  const float* s = (blockIdx.y == 0) ? s0 : (blockIdx.y == 1) ? s1 : s2;
  ushort* o      = (blockIdx.y == 0) ? o0 : (blockIdx.y == 1) ? o1 : o2;
  float4 v = reinterpret_cast<const float4*>(s)[i];
  ushort4 t = make_ushort4(f2b(v.x), f2b(v.y), f2b(v.z), f2b(v.w));
  reinterpret_cast<ushort4*>(o)[i] = t;
}

// gates: f = (1+e^-ip)/(2+e^-fp+e^-ip), i = 1-f, h~ = hp>=0 ? hp+0.5 : sigmoid(hp)
__device__ __forceinline__ void gates(float fp, float ip, float hp, float& a, float& v) {
  float Ef = __expf(-fp);
  float Ei = __expf(-ip);
  float r  = __builtin_amdgcn_rcpf(2.f + Ef + Ei);
  float f  = (1.f + Ei) * r;
  float i  = (1.f + Ef) * r;
  float ht = (hp >= 0.f) ? (hp + 0.5f) : __builtin_amdgcn_rcpf(1.f + __expf(-hp));
  a = f;
  v = i * ht;
}

// 256x256 single-gate GEMM, 8-phase template (m201-derived): 4 phases/K-tile,
// halves = K-halves {A-kh0,B-kh0,A-kh1,B-kh1}, stage schedule ph1->H4(t+1),
// ph2-4 -> H1-H3(t+2), single vmcnt(6)+BAR per tile, counted never-drain.
__launch_bounds__(GTPB, 2)
__global__ void gemm256(const ushort* __restrict__ X,
                        const ushort* __restrict__ W0, const ushort* __restrict__ W1,
                        const ushort* __restrict__ W2,
                        const float* __restrict__ bfp, const float* __restrict__ bip,
                        const float* __restrict__ bhp,
                        ushort* __restrict__ P0, ushort* __restrict__ P1, ushort* __restrict__ P2)
{
  __shared__ ushort lds_f[8 * 8192];  // [slot][kh][mat][256*32] halfwords = 128 KiB
#define REGB(sl, kh, mat) (&lds_f[((((sl) * 2 + (kh)) * 2 + (mat)) * 8192)])

  // bijective XCD swizzle over 768 blocks
  const int id  = blockIdx.x;
  const int swz = (id & 7) * 96 + (id >> 3);
  const int z   = swz >> 8;            // gate
  const int rem = swz & 255;
  const int n0  = (rem >> 6) * 256;
  const int m0  = (rem & 63) * 256;

  const ushort* W = (z == 0) ? W0 : (z == 1) ? W1 : W2;
  ushort*       P = (z == 0) ? P0 : (z == 1) ? P1 : P2;
  const float*  bias = (z == 0) ? bfp : (z == 1) ? bip : bhp;

  const int tid  = threadIdx.x;
  const int lane = tid & 63;
  const int w    = tid >> 6;          // 0..7
  const int wr   = w >> 2;            // 0..1 : 128-row strip
  const int wc   = w & 3;             // 0..3 : 64-col strip
  const int fr   = lane & 15, g = lane >> 4;

  // ---- ds_read offsets within a (kh,mat) region: row*32 + (g^((row>>1)&3))*8 ----
  int aoff[8], boff[4];
#pragma unroll
  for (int q = 0; q < 8; ++q) {
    int row = wr * 128 + q * 16 + fr;
    aoff[q] = row * 32 + ((g ^ ((row >> 1) & 3)) << 3);
  }
#pragma unroll
  for (int n = 0; n < 4; ++n) {
    int row = wc * 64 + n * 16 + fr;
    boff[n] = row * 32 + ((g ^ ((row >> 1) & 3)) << 3);
  }

  // ---- staging: thread covers rows r0 and r0+128 at k16-slot k0 (inverse swizzle) ----
  const int r0 = tid >> 2;
  const int k0 = (tid & 3) ^ ((r0 >> 1) & 3);
  const ushort* Xp = X + (size_t)m0 * K_DIM;
  const ushort* Wp = W + (size_t)n0 * K_DIM;

  auto stage = [&](int slot, int kh, int mat, int kt) {
    const ushort* base = mat ? Wp : Xp;
    const ushort* s_ = base + (size_t)r0 * K_DIM + kt * BK2 + kh * 32 + k0 * 8;
    ushort* d_ = REGB(slot, kh, mat) + tid * 8;
    __builtin_amdgcn_global_load_lds((const AS1 void*)s_, (AS3 void*)d_, 16, 0, 0);
    __builtin_amdgcn_global_load_lds((const AS1 void*)(s_ + (size_t)128 * K_DIM),
                                     (AS3 void*)(d_ + 4096), 16, 0, 0);
  };

  f32x4 acc[8][4] = {};

  // prologue: t0 H1-H4; vmcnt(4) [H1,H2 in]; BAR; t1 H1-H3; vmcnt(6) [t0 all in]; BAR
  stage(0, 0, 0, 0); stage(0, 0, 1, 0); stage(0, 1, 0, 0); stage(0, 1, 1, 0);
  WAITV4(); BAR(); SB0();
  stage(1, 0, 0, 1); stage(1, 0, 1, 1); stage(1, 1, 0, 1);
  WAITV6(); BAR(); SB0();

  v8s aF[4], bF[4];
  for (int t = 0; t < NT2; ++t) {
    const int sl = t & 1, so = sl ^ 1;

    // ---- phase 1: ks=0, m-frags 0-3 (reads H1,H2 of tile t) ----
#pragma unroll
    for (int q = 0; q < 4; ++q) aF[q] = *reinterpret_cast<const v8s*>(REGB(sl, 0, 0) + aoff[q]);
#pragma unroll
    for (int n = 0; n < 4; ++n) bF[n] = *reinterpret_cast<const v8s*>(REGB(sl, 0, 1) + boff[n]);
    SB0();
    if (t + 1 < NT2) stage(so, 1, 1, t + 1);           // H4(t+1)
    SB0(); BAR(); WAITL0();
    __builtin_amdgcn_s_setprio(1);
#pragma unroll
    for (int q = 0; q < 4; ++q)
#pragma unroll
      for (int n = 0; n < 4; ++n)
        acc[q][n] = __builtin_amdgcn_mfma_f32_16x16x32_bf16(aF[q], bF[n], acc[q][n], 0, 0, 0);
    __builtin_amdgcn_s_setprio(0);
    BAR(); SB0();

    // ---- phase 2: ks=0, m-frags 4-7 (B regs reused) ----
#pragma unroll
    for (int q = 0; q < 4; ++q) aF[q] = *reinterpret_cast<const v8s*>(REGB(sl, 0, 0) + aoff[4 + q]);
    SB0();
    if (t + 2 < NT2) stage(sl, 0, 0, t + 2);           // H1(t+2)
    SB0(); BAR(); WAITL0();
    __builtin_amdgcn_s_setprio(1);
#pragma unroll
    for (int q = 0; q < 4; ++q)
#pragma unroll
      for (int n = 0; n < 4; ++n)
        acc[4 + q][n] = __builtin_amdgcn_mfma_f32_16x16x32_bf16(aF[q], bF[n], acc[4 + q][n], 0, 0, 0);
    __builtin_amdgcn_s_setprio(0);
    BAR(); SB0();

    // ---- phase 3: ks=1, m-frags 0-3 (reads H3,H4 of tile t) ----
#pragma unroll
    for (int q = 0; q < 4; ++q) aF[q] = *reinterpret_cast<const v8s*>(REGB(sl, 1, 0) + aoff[q]);
#pragma unroll
    for (int n = 0; n < 4; ++n) bF[n] = *reinterpret_cast<const v8s*>(REGB(sl, 1, 1) + boff[n]);
    SB0();
    if (t + 2 < NT2) stage(sl, 0, 1, t + 2);           // H2(t+2)
    SB0(); BAR(); WAITL0();
    __builtin_amdgcn_s_setprio(1);
#pragma unroll
    for (int q = 0; q < 4; ++q)
#pragma unroll
      for (int n = 0; n < 4; ++n)
        acc[q][n] = __builtin_amdgcn_mfma_f32_16x16x32_bf16(aF[q], bF[n], acc[q][n], 0, 0, 0);
    __builtin_amdgcn_s_setprio(0);
    BAR(); SB0();

    // ---- phase 4: ks=1, m-frags 4-7; per-tile counted wait-then-barrier ----
#pragma unroll
    for (int q = 0; q < 4; ++q) aF[q] = *reinterpret_cast<const v8s*>(REGB(sl, 1, 0) + aoff[4 + q]);
    SB0();
    if (t + 2 < NT2) stage(sl, 1, 0, t + 2);           // H3(t+2)
    SB0();
    if (t + 2 < NT2)      { WAITV6(); }                // retires all of t+1
    else if (t + 1 < NT2) { WAITV0(); }                // drain: t+1 (=last) all in
    BAR(); WAITL0();
    __builtin_amdgcn_s_setprio(1);
#pragma unroll
    for (int q = 0; q < 4; ++q)
#pragma unroll
      for (int n = 0; n < 4; ++n)
        acc[4 + q][n] = __builtin_amdgcn_mfma_f32_16x16x32_bf16(aF[q], bF[n], acc[4 + q][n], 0, 0, 0);
    __builtin_amdgcn_s_setprio(0);
    if (t + 1 < NT2) { BAR(); SB0(); }
  }

  // epilogue: C/D layout col=lane&15, row=(lane>>4)*4+r [m89]; bias added here
#pragma unroll
  for (int q = 0; q < 8; ++q) {
    const int row0 = m0 + wr * 128 + q * 16 + g * 4;
#pragma unroll
    for (int n = 0; n < 4; ++n) {
      const int col = n0 + wc * 64 + n * 16 + fr;
      const float bv = bias[col];
#pragma unroll
      for (int r = 0; r < 4; ++r)
        P[(size_t)(row0 + r) * N_DIM + col] = f2b(acc[q][n][r] + bv);
    }
  }
#undef REGB
}

// pass1: gates from 3 preact streams; per-chunk aggregates; REWRITE Pf<-a, Ph<-v
// (same element, same thread, same iteration -> race-free in-place)
__global__ void scan_pass1g(ushort4* __restrict__ Pf4, const ushort4* __restrict__ Pi4,
                            ushort4* __restrict__ Ph4,
                            float4* __restrict__ AggA, float4* __restrict__ AggV)
{
  int tid = blockIdx.x * blockDim.x + threadIdx.x;   // 65536
  int c4 = tid & 1023;
  int chunk = tid >> 10;
  int b = c4 >> 8;
  int d4 = c4 & 255;
  size_t base = ((size_t)b * L_SEQ + (size_t)chunk * CH) * 256 + d4;
  float A0 = 1.f, A1 = 1.f, A2 = 1.f, A3 = 1.f;
  float V0 = 0.f, V1 = 0.f, V2 = 0.f, V3 = 0.f;
#pragma unroll 2
  for (int t = 0; t < CH; ++t) {
    size_t idx = base + (size_t)t * 256;
    ushort4 uf = Pf4[idx], ui = Pi4[idx], uh = Ph4[idx];
    float a0, v0, a1, v1, a2, v2, a3, v3;
    gates(b2f(uf.x), b2f(ui.x), b2f(uh.x), a0, v0); A0 *= a0; V0 = fmaf(a0, V0, v0);
    gates(b2f(uf.y), b2f(ui.y), b2f(uh.y), a1, v1); A1 *= a1; V1 = fmaf(a1, V1, v1);
    gates(b2f(uf.z), b2f(ui.z), b2f(uh.z), a2, v2); A2 *= a2; V2 = fmaf(a2, V2, v2);
    gates(b2f(uf.w), b2f(ui.w), b2f(uh.w), a3, v3); A3 *= a3; V3 = fmaf(a3, V3, v3);
    Pf4[idx] = make_ushort4(f2b(a0), f2b(a1), f2b(a2), f2b(a3));
    Ph4[idx] = make_ushort4(f2b(v0), f2b(v1), f2b(v2), f2b(v3));
  }
  AggA[(size_t)chunk * (NCHAN / 4) + c4] = make_float4(A0, A1, A2, A3);
  AggV[(size_t)chunk * (NCHAN / 4) + c4] = make_float4(V0, V1, V2, V3);
}

// mid: sequential combine across chunk aggregates, 4 channels per thread
__global__ void scan_mid(const float4* __restrict__ AggA, const float4* __restrict__ AggV,
                         float4* __restrict__ Start)
{
  int c4 = blockIdx.x * blockDim.x + threadIdx.x;   // 1024
  float4 h = make_float4(0.f, 0.f, 0.f, 0.f);
#pragma unroll
  for (int j = 0; j < NCHUNK; ++j) {
    float4 A = AggA[(size_t)j * (NCHAN / 4) + c4];
    float4 V = AggV[(size_t)j * (NCHAN / 4) + c4];
    Start[(size_t)j * (NCHAN / 4) + c4] = h;
    h.x = fmaf(A.x, h.x, V.x);
    h.y = fmaf(A.y, h.y, V.y);
    h.z = fmaf(A.z, h.z, V.z);
    h.w = fmaf(A.w, h.w, V.w);
  }
}

// pass2: gate-free replay from (a in Pf, v in Ph), write h (f32)
__global__ void scan_pass2b(const ushort4* __restrict__ Pa4, const ushort4* __restrict__ Pv4,
                            const float4* __restrict__ Start, float4* __restrict__ out4)
{
  int tid = blockIdx.x * blockDim.x + threadIdx.x;   // 65536
  int c4 = tid & 1023;
  int chunk = tid >> 10;
  int b = c4 >> 8;
  int d4 = c4 & 255;
  size_t base = ((size_t)b * L_SEQ + (size_t)chunk * CH) * 256 + d4;
  float4 h = Start[(size_t)chunk * (NCHAN / 4) + c4];
#pragma unroll 4
  for (int t = 0; t < CH; ++t) {
    size_t idx = base + (size_t)t * 256;
    ushort4 ua = Pa4[idx], uv = Pv4[idx];
    h.x = fmaf(b2f(ua.x), h.x, b2f(uv.x));
    h.y = fmaf(b2f(ua.y), h.y, b2f(uv.y));
    h.z = fmaf(b2f(ua.z), h.z, b2f(uv.z));
    h.w = fmaf(b2f(ua.w), h.w, b2f(uv.w));
    out4[idx] = h;
  }
}

extern "C" void kernel_launch(void* const* d_in, const int* in_sizes, int n_in,
                              void* d_out, int out_size, void* d_ws, size_t ws_size,
                              hipStream_t stream) {
  (void)in_sizes; (void)n_in; (void)out_size; (void)ws_size;
  const float* x  = (const float*)d_in[0];
  const float* Wf = (const float*)d_in[1];
  const float* bf = (const float*)d_in[2];
  const float* Wi = (const float*)d_in[3];
  const float* bi = (const float*)d_in[4];
  const float* Wh = (const float*)d_in[5];
  const float* bh = (const float*)d_in[6];

  // workspace (~143 MB, proven-safe size)
  ushort* xb  = (ushort*)d_ws;                         // 33.5 MB
  ushort* wfb = xb  + (size_t)M_TOTAL * K_DIM;
  ushort* wib = wfb + (size_t)N_DIM * K_DIM;
  ushort* whb = wib + (size_t)N_DIM * K_DIM;
  ushort* Pf  = whb + (size_t)N_DIM * K_DIM;           // 33.5 MB each
  ushort* Pi  = Pf  + (size_t)M_TOTAL * N_DIM;
  ushort* Ph  = Pi  + (size_t)M_TOTAL * N_DIM;
  float*  AggA  = (float*)(Ph + (size_t)M_TOTAL * N_DIM);
  float*  AggV  = AggA + NCHAN * NCHUNK;
  float*  Start = AggV + NCHAN * NCHUNK;

  cast_f32_bf16<<<(M_TOTAL * K_DIM / 4) / 256, 256, 0, stream>>>(x, xb, M_TOTAL * K_DIM / 4);
  cast_w3<<<dim3((N_DIM * K_DIM / 4) / 256, 3), 256, 0, stream>>>(Wf, Wi, Wh, wfb, wib, whb);

  gemm256<<<dim3(768), GTPB, 0, stream>>>(xb, wfb, wib, whb, bf, bi, bh, Pf, Pi, Ph);

  scan_pass1g<<<(NCHAN / 4 * NCHUNK) / 256, 256, 0, stream>>>(
      (ushort4*)Pf, (const ushort4*)Pi, (ushort4*)Ph, (float4*)AggA, (float4*)AggV);
  scan_mid<<<(NCHAN / 4) / 256, 256, 0, stream>>>(
      (const float4*)AggA, (const float4*)AggV, (float4*)Start);
  scan_pass2b<<<(NCHAN / 4 * NCHUNK) / 256, 256, 0, stream>>>(
      (const ushort4*)Pf, (const ushort4*)Ph, (const float4*)Start, (float4*)d_out);
}

// Round 13
// 169.856 us; speedup vs baseline: 1.2673x; 1.2673x over previous
//
#include <hip/hip_runtime.h>

// ---- problem geometry ----
#define M_TOTAL 16384          // B*L
#define N_DIM   1024           // D
#define K_DIM   1024
#define L_SEQ   4096
#define B_SZ    4
#define D_DIM   1024
#define CH      64             // scan chunk length (== wave row-strip)
#define NCHUNK  (L_SEQ / CH)   // 64
#define NCHAN   (B_SZ * D_DIM) // 4096

// ---- GEMM tile ----
#define BM 128
#define BN 128
#define BK 64
#define NKT (K_DIM / BK)       // 16
#define TPB 512                // 8 waves: 2M x 4N, wave tile 64x32

typedef __attribute__((ext_vector_type(8))) short v8s;
typedef __attribute__((ext_vector_type(4))) float f32x4;

#define SB0()   __builtin_amdgcn_sched_barrier(0)
#define BAR()   __builtin_amdgcn_s_barrier()
#define WAITL0() do { asm volatile("s_waitcnt lgkmcnt(0)" ::: "memory"); SB0(); } while (0)
#define WAITL4() do { asm volatile("s_waitcnt lgkmcnt(4)" ::: "memory"); SB0(); } while (0)
#define WAITV0() do { asm volatile("s_waitcnt vmcnt(0)"   ::: "memory"); SB0(); } while (0)
#define AS1 __attribute__((address_space(1)))
#define AS3 __attribute__((address_space(3)))

__device__ __forceinline__ ushort f2b(float f) {
  uint u = __float_as_uint(f);
  u += 0x7FFFu + ((u >> 16) & 1u);   // RNE (finite inputs)
  return (ushort)(u >> 16);
}
__device__ __forceinline__ float b2f(ushort u) {
  return __uint_as_float(((uint)u) << 16);
}

__global__ void cast_f32_bf16(const float* __restrict__ src, ushort* __restrict__ dst, int n4) {
  int i = blockIdx.x * blockDim.x + threadIdx.x;
  if (i >= n4) return;
  float4 v = reinterpret_cast<const float4*>(src)[i];
  ushort4 o = make_ushort4(f2b(v.x), f2b(v.y), f2b(v.z), f2b(v.w));
  reinterpret_cast<ushort4*>(dst)[i] = o;
}

__global__ void cast_w3(const float* __restrict__ s0, const float* __restrict__ s1,
                        const float* __restrict__ s2,
                        ushort* __restrict__ o0, ushort* __restrict__ o1, ushort* __restrict__ o2) {
  int i = blockIdx.x * blockDim.x + threadIdx.x;
  const float* s = (blockIdx.y == 0) ? s0 : (blockIdx.y == 1) ? s1 : s2;
  ushort* o      = (blockIdx.y == 0) ? o0 : (blockIdx.y == 1) ? o1 : o2;
  float4 v = reinterpret_cast<const float4*>(s)[i];
  ushort4 t = make_ushort4(f2b(v.x), f2b(v.y), f2b(v.z), f2b(v.w));
  reinterpret_cast<ushort4*>(o)[i] = t;
}

// gates: f = (1+e^-ip)/(2+e^-fp+e^-ip), i = 1-f, h~ = hp>=0 ? hp+0.5 : sigmoid(hp)
__device__ __forceinline__ void gates(float fp, float ip, float hp, float& a, float& v) {
  float Ef = __expf(-fp);
  float Ei = __expf(-ip);
  float r  = __builtin_amdgcn_rcpf(2.f + Ef + Ei);
  float f  = (1.f + Ei) * r;
  float i  = (1.f + Ef) * r;
  float ht = (hp >= 0.f) ? (hp + 0.5f) : __builtin_amdgcn_rcpf(1.f + __expf(-hp));
  a = f;
  v = i * ht;
}

// Fused 3-GEMM (R10 structure, measured 126 us): BK=64, 2 LDS dbuf, one barrier
// + one vmcnt(0) per K-tile, counted-lgkm 3-phase ladder. Epilogue additionally
// computes per-chunk scan aggregates in-register (ordered shfl_xor butterfly
// over g, ordered fold over mi) -> scan_pass1 eliminated.
__launch_bounds__(TPB, 2)
__global__ void gemm_fused(const ushort* __restrict__ X,
                           const ushort* __restrict__ W0, const ushort* __restrict__ W1,
                           const ushort* __restrict__ W2,
                           const float* __restrict__ bfp, const float* __restrict__ bip,
                           const float* __restrict__ bhp,
                           uint* __restrict__ Pav,
                           float* __restrict__ AggA, float* __restrict__ AggV)
{
  __shared__ ushort lds[2][4][BM * BK];   // [buf][A,Bf,Bi,Bh]  2 x 64 KiB = 128 KiB

  // bijective XCD swizzle, 1024 blocks
  const int id  = blockIdx.x;
  const int sw  = (id & 7) * 128 + (id >> 3);
  const int n0  = (sw & 7) * BN;
  const int m0  = (sw >> 3) * BM;

  const int tid  = threadIdx.x;
  const int lane = tid & 63;
  const int w    = tid >> 6;          // 0..7
  const int wr   = w >> 2;            // 0..1 : 64-row strip (== one scan chunk)
  const int wc   = w & 3;             // 0..3 : 32-col strip
  const int fr   = lane & 15, g = lane >> 4;

  // ---- swizzled ds_read offsets (halfwords): 16B slot (ks*4+g) ^ (row&7) ----
  int aoffh[4][2], boffh[2][2];
#pragma unroll
  for (int q = 0; q < 4; ++q)
#pragma unroll
    for (int ks = 0; ks < 2; ++ks) {
      int row = wr * 64 + q * 16 + fr;
      aoffh[q][ks] = row * BK + (((ks * 4 + g) ^ (row & 7)) << 3);
    }
#pragma unroll
  for (int n = 0; n < 2; ++n)
#pragma unroll
    for (int ks = 0; ks < 2; ++ks) {
      int row = wc * 32 + n * 16 + fr;
      boffh[n][ks] = row * BK + (((ks * 4 + g) ^ (row & 7)) << 3);
    }

  // ---- staging: 2 x 16B slots per matrix per thread; inverse-swizzled source ----
  const int s0 = tid, s1 = 512 + tid;
  const int r0 = s0 >> 3, k0 = (s0 & 7) ^ (r0 & 7);
  const int r1 = s1 >> 3, k1 = (s1 & 7) ^ (r1 & 7);
  const int d0 = s0 * 8, d1 = s1 * 8;   // halfword dest offsets

  const ushort* gsrc[4][2];
  gsrc[0][0] = X  + (size_t)(m0 + r0) * K_DIM + k0 * 8;
  gsrc[0][1] = X  + (size_t)(m0 + r1) * K_DIM + k1 * 8;
  gsrc[1][0] = W0 + (size_t)(n0 + r0) * K_DIM + k0 * 8;
  gsrc[1][1] = W0 + (size_t)(n0 + r1) * K_DIM + k1 * 8;
  gsrc[2][0] = W1 + (size_t)(n0 + r0) * K_DIM + k0 * 8;
  gsrc[2][1] = W1 + (size_t)(n0 + r1) * K_DIM + k1 * 8;
  gsrc[3][0] = W2 + (size_t)(n0 + r0) * K_DIM + k0 * 8;
  gsrc[3][1] = W2 + (size_t)(n0 + r1) * K_DIM + k1 * 8;

  auto issue = [&](int buf, int mat, int kt, int j) {
    const ushort* s_ = gsrc[mat][j] + kt * BK;
    __builtin_amdgcn_global_load_lds((const AS1 void*)s_,
        (AS3 void*)(&lds[buf][mat][j ? d1 : d0]), 16, 0, 0);
  };

  f32x4 acc[3][4][2] = {};

  // prologue: stage tile 0 fully, drain, barrier
#pragma unroll
  for (int mat = 0; mat < 4; ++mat) { issue(0, mat, 0, 0); issue(0, mat, 0, 1); }
  WAITV0();
  BAR(); SB0();

  int cur = 0;
  for (int t = 0; t < NKT; ++t) {
    const bool pf = (t + 1 < NKT);
    const ushort* rb = &lds[cur][0][0];
    v8s aF[4][2], bA[2][2], bB[2][2];

    // ---- issue group 1: aF + bA<-B0  (12 ds_reads) ----
#pragma unroll
    for (int q = 0; q < 4; ++q)
#pragma unroll
      for (int ks = 0; ks < 2; ++ks)
        aF[q][ks] = *reinterpret_cast<const v8s*>(rb + aoffh[q][ks]);
#pragma unroll
    for (int n = 0; n < 2; ++n)
#pragma unroll
      for (int ks = 0; ks < 2; ++ks)
        bA[n][ks] = *reinterpret_cast<const v8s*>(rb + 1 * BM * BK + boffh[n][ks]);
    SB0();
    if (pf) {
#pragma unroll
      for (int mat = 0; mat < 4; ++mat) { issue(cur ^ 1, mat, t + 1, 0); issue(cur ^ 1, mat, t + 1, 1); }
    }
    SB0();
    // ---- issue group 2: bB<-B1 (4 ds_reads)  [outstanding: 16] ----
#pragma unroll
    for (int n = 0; n < 2; ++n)
#pragma unroll
      for (int ks = 0; ks < 2; ++ks)
        bB[n][ks] = *reinterpret_cast<const v8s*>(rb + 2 * BM * BK + boffh[n][ks]);
    SB0();
    WAITL4();   // aF + bA landed; bB in flight
    __builtin_amdgcn_s_setprio(1);
#pragma unroll
    for (int ks = 0; ks < 2; ++ks)
#pragma unroll
      for (int mi = 0; mi < 4; ++mi) {
        acc[0][mi][0] = __builtin_amdgcn_mfma_f32_16x16x32_bf16(aF[mi][ks], bA[0][ks], acc[0][mi][0], 0, 0, 0);
        acc[0][mi][1] = __builtin_amdgcn_mfma_f32_16x16x32_bf16(aF[mi][ks], bA[1][ks], acc[0][mi][1], 0, 0, 0);
      }
    __builtin_amdgcn_s_setprio(0);
    // ---- issue group 3: bA<-B2 (4 ds_reads)  [outstanding: 8] ----
#pragma unroll
    for (int n = 0; n < 2; ++n)
#pragma unroll
      for (int ks = 0; ks < 2; ++ks)
        bA[n][ks] = *reinterpret_cast<const v8s*>(rb + 3 * BM * BK + boffh[n][ks]);
    SB0();
    WAITL4();   // bB landed; bA(B2) in flight
    __builtin_amdgcn_s_setprio(1);
#pragma unroll
    for (int ks = 0; ks < 2; ++ks)
#pragma unroll
      for (int mi = 0; mi < 4; ++mi) {
        acc[1][mi][0] = __builtin_amdgcn_mfma_f32_16x16x32_bf16(aF[mi][ks], bB[0][ks], acc[1][mi][0], 0, 0, 0);
        acc[1][mi][1] = __builtin_amdgcn_mfma_f32_16x16x32_bf16(aF[mi][ks], bB[1][ks], acc[1][mi][1], 0, 0, 0);
      }
    __builtin_amdgcn_s_setprio(0);
    WAITL0();   // bA(B2) landed
    __builtin_amdgcn_s_setprio(1);
#pragma unroll
    for (int ks = 0; ks < 2; ++ks)
#pragma unroll
      for (int mi = 0; mi < 4; ++mi) {
        acc[2][mi][0] = __builtin_amdgcn_mfma_f32_16x16x32_bf16(aF[mi][ks], bA[0][ks], acc[2][mi][0], 0, 0, 0);
        acc[2][mi][1] = __builtin_amdgcn_mfma_f32_16x16x32_bf16(aF[mi][ks], bA[1][ks], acc[2][mi][1], 0, 0, 0);
      }
    __builtin_amdgcn_s_setprio(0);

    // ---- tile boundary: single drain + single barrier (wait-then-barrier) ----
    if (pf) {
      WAITV0();
      BAR(); SB0();
      cur ^= 1;
    }
  }

  // ---- epilogue: pack (a,v) AND build per-chunk scan aggregates ----
  // combine (X then Y): A = AX*AY, V = AY*VX + VY   (associative)
  const int bidx = m0 >> 12;                 // batch
  const int jch  = ((m0 & 4095) >> 6) + wr;  // per-batch chunk index of this strip
#pragma unroll
  for (int ni = 0; ni < 2; ++ni) {
    const int col = n0 + wc * 32 + ni * 16 + fr;
    const float vbf = bfp[col], vbi = bip[col], vbh = bhp[col];
    float BAgg[4], VAgg[4];
#pragma unroll
    for (int mi = 0; mi < 4; ++mi) {
      const int row0 = m0 + wr * 64 + mi * 16 + g * 4;
      float RA = 1.f, RV = 0.f;
#pragma unroll
      for (int r = 0; r < 4; ++r) {
        float a, v;
        gates(acc[0][mi][ni][r] + vbf, acc[1][mi][ni][r] + vbi, acc[2][mi][ni][r] + vbh, a, v);
        Pav[(size_t)(row0 + r) * N_DIM + col] = (uint)f2b(a) | ((uint)f2b(v) << 16);
        RA *= a; RV = fmaf(a, RV, v);
      }
      // ordered combine across g (runs at rows mi*16 + g*4): 2 xor rounds
      {
        float pA = __shfl_xor(RA, 16), pV = __shfl_xor(RV, 16);
        if (((lane >> 4) & 1) == 0) { RV = fmaf(pA, RV, pV); RA = RA * pA; }
        else                        { RV = fmaf(RA, pV, RV); RA = RA * pA; }
        pA = __shfl_xor(RA, 32); pV = __shfl_xor(RV, 32);
        if (((lane >> 5) & 1) == 0) { RV = fmaf(pA, RV, pV); RA = RA * pA; }
        else                        { RV = fmaf(RA, pV, RV); RA = RA * pA; }
      }
      BAgg[mi] = RA; VAgg[mi] = RV;
    }
    // ordered fold over mi (blocks of 16 rows)
    float CA = BAgg[0], CV = VAgg[0];
#pragma unroll
    for (int mi = 1; mi < 4; ++mi) { CV = fmaf(BAgg[mi], CV, VAgg[mi]); CA *= BAgg[mi]; }
    if (g == 0) {
      const int c = bidx * D_DIM + col;
      AggA[jch * NCHAN + c] = CA;
      AggV[jch * NCHAN + c] = CV;
    }
  }
}

// mid: sequential combine across chunk aggregates, 4 channels per thread
__global__ void scan_mid(const float4* __restrict__ AggA, const float4* __restrict__ AggV,
                         float4* __restrict__ Start)
{
  int c4 = blockIdx.x * blockDim.x + threadIdx.x;   // 1024
  float4 h = make_float4(0.f, 0.f, 0.f, 0.f);
#pragma unroll
  for (int j = 0; j < NCHUNK; ++j) {
    float4 A = AggA[(size_t)j * (NCHAN / 4) + c4];
    float4 V = AggV[(size_t)j * (NCHAN / 4) + c4];
    Start[(size_t)j * (NCHAN / 4) + c4] = h;
    h.x = fmaf(A.x, h.x, V.x);
    h.y = fmaf(A.y, h.y, V.y);
    h.z = fmaf(A.z, h.z, V.z);
    h.w = fmaf(A.w, h.w, V.w);
  }
}

// pass2: replay each chunk with true carry, 4 channels per thread, float4 out
__global__ void scan_pass2(const uint4* __restrict__ Pav4,
                           const float4* __restrict__ Start, float4* __restrict__ out4)
{
  int tid = blockIdx.x * blockDim.x + threadIdx.x;   // 65536
  int c4 = tid & 1023;
  int chunk = tid >> 10;
  int b = c4 >> 8;
  int d4 = c4 & 255;
  size_t base4 = ((size_t)b * L_SEQ + (size_t)chunk * CH) * (D_DIM / 4) + d4;
  float4 h = Start[(size_t)chunk * (NCHAN / 4) + c4];
#pragma unroll 4
  for (int t = 0; t < CH; ++t) {
    size_t idx = base4 + (size_t)t * (D_DIM / 4);
    uint4 u = Pav4[idx];
    h.x = fmaf(b2f((ushort)(u.x & 0xFFFFu)), h.x, b2f((ushort)(u.x >> 16)));
    h.y = fmaf(b2f((ushort)(u.y & 0xFFFFu)), h.y, b2f((ushort)(u.y >> 16)));
    h.z = fmaf(b2f((ushort)(u.z & 0xFFFFu)), h.z, b2f((ushort)(u.z >> 16)));
    h.w = fmaf(b2f((ushort)(u.w & 0xFFFFu)), h.w, b2f((ushort)(u.w >> 16)));
    out4[idx] = h;
  }
}

extern "C" void kernel_launch(void* const* d_in, const int* in_sizes, int n_in,
                              void* d_out, int out_size, void* d_ws, size_t ws_size,
                              hipStream_t stream) {
  (void)in_sizes; (void)n_in; (void)out_size; (void)ws_size;
  const float* x  = (const float*)d_in[0];
  const float* Wf = (const float*)d_in[1];
  const float* bf = (const float*)d_in[2];
  const float* Wi = (const float*)d_in[3];
  const float* bi = (const float*)d_in[4];
  const float* Wh = (const float*)d_in[5];
  const float* bh = (const float*)d_in[6];

  // workspace (~107 MB)
  ushort* xb  = (ushort*)d_ws;                         // 33.5 MB
  ushort* wfb = xb  + (size_t)M_TOTAL * K_DIM;
  ushort* wib = wfb + (size_t)N_DIM * K_DIM;
  ushort* whb = wib + (size_t)N_DIM * K_DIM;
  uint*  Pav  = (uint*)(whb + (size_t)N_DIM * K_DIM);  // 67 MB packed (a,v)
  float* AggA  = (float*)(Pav + (size_t)M_TOTAL * N_DIM);
  float* AggV  = AggA + NCHAN * NCHUNK;
  float* Start = AggV + NCHAN * NCHUNK;

  cast_f32_bf16<<<(M_TOTAL * K_DIM / 4) / 256, 256, 0, stream>>>(x, xb, M_TOTAL * K_DIM / 4);
  cast_w3<<<dim3((N_DIM * K_DIM / 4) / 256, 3), 256, 0, stream>>>(Wf, Wi, Wh, wfb, wib, whb);

  gemm_fused<<<dim3((M_TOTAL / BM) * (N_DIM / BN)), TPB, 0, stream>>>(
      xb, wfb, wib, whb, bf, bi, bh, Pav, AggA, AggV);

  scan_mid<<<(NCHAN / 4) / 256, 256, 0, stream>>>(
      (const float4*)AggA, (const float4*)AggV, (float4*)Start);
  scan_pass2<<<(NCHAN / 4 * NCHUNK) / 256, 256, 0, stream>>>(
      (const uint4*)Pav, (const float4*)Start, (float4*)d_out);
}

// Round 14
// 164.171 us; speedup vs baseline: 1.3111x; 1.0346x over previous
//
#include <hip/hip_runtime.h>

// ---- problem geometry ----
#define M_TOTAL 16384          // B*L
#define N_DIM   1024           // D
#define K_DIM   1024
#define L_SEQ   4096
#define B_SZ    4
#define D_DIM   1024
#define CH      64             // scan chunk length (== wave row-strip)
#define NCHUNK  (L_SEQ / CH)   // 64
#define NCHAN   (B_SZ * D_DIM) // 4096

// ---- GEMM tile ----
#define BM 128
#define BN 128
#define BK 64
#define NKT (K_DIM / BK)       // 16
#define TPB 512                // 8 waves: 2M x 4N, wave tile 64x32

typedef __attribute__((ext_vector_type(8))) short v8s;
typedef __attribute__((ext_vector_type(4))) float f32x4;

#define SB0()   __builtin_amdgcn_sched_barrier(0)
#define BAR()   __builtin_amdgcn_s_barrier()
#define WAITL0() do { asm volatile("s_waitcnt lgkmcnt(0)" ::: "memory"); SB0(); } while (0)
#define WAITL4() do { asm volatile("s_waitcnt lgkmcnt(4)" ::: "memory"); SB0(); } while (0)
#define WAITV0() do { asm volatile("s_waitcnt vmcnt(0)"   ::: "memory"); SB0(); } while (0)
#define AS1 __attribute__((address_space(1)))
#define AS3 __attribute__((address_space(3)))

__device__ __forceinline__ ushort f2b(float f) {
  uint u = __float_as_uint(f);
  u += 0x7FFFu + ((u >> 16) & 1u);   // RNE (finite inputs)
  return (ushort)(u >> 16);
}
__device__ __forceinline__ float b2f(ushort u) {
  return __uint_as_float(((uint)u) << 16);
}
__device__ __forceinline__ uint cvtpk(float lo, float hi) {  // bf16(lo) | bf16(hi)<<16, HW RNE
  uint r;
  asm("v_cvt_pk_bf16_f32 %0, %1, %2" : "=v"(r) : "v"(lo), "v"(hi));
  return r;
}

__global__ void cast_w3(const float* __restrict__ s0, const float* __restrict__ s1,
                        const float* __restrict__ s2,
                        ushort* __restrict__ o0, ushort* __restrict__ o1, ushort* __restrict__ o2) {
  int i = blockIdx.x * blockDim.x + threadIdx.x;
  const float* s = (blockIdx.y == 0) ? s0 : (blockIdx.y == 1) ? s1 : s2;
  ushort* o      = (blockIdx.y == 0) ? o0 : (blockIdx.y == 1) ? o1 : o2;
  float4 v = reinterpret_cast<const float4*>(s)[i];
  ushort4 t = make_ushort4(f2b(v.x), f2b(v.y), f2b(v.z), f2b(v.w));
  reinterpret_cast<ushort4*>(o)[i] = t;
}

// gates: f = (1+e^-ip)/(2+e^-fp+e^-ip), i = 1-f, h~ = hp>=0 ? hp+0.5 : sigmoid(hp)
__device__ __forceinline__ void gates(float fp, float ip, float hp, float& a, float& v) {
  float Ef = __expf(-fp);
  float Ei = __expf(-ip);
  float r  = __builtin_amdgcn_rcpf(2.f + Ef + Ei);
  float f  = (1.f + Ei) * r;
  float i  = (1.f + Ef) * r;
  float ht = (hp >= 0.f) ? (hp + 0.5f) : __builtin_amdgcn_rcpf(1.f + __expf(-hp));
  a = f;
  v = i * ht;
}

// Fused 3-GEMM (R10/R13 structure) with A-staging from f32 x directly:
// group-1 issues f32 A-loads for t+1; boundary converts (cvt_pk RNE) and
// ds_writes into the same linear LDS layout. B via global_load_lds unchanged.
// Epilogue packs (a,v) and builds per-chunk scan aggregates (shfl butterfly).
__launch_bounds__(TPB, 2)
__global__ void gemm_fused(const float* __restrict__ Xf,
                           const ushort* __restrict__ W0, const ushort* __restrict__ W1,
                           const ushort* __restrict__ W2,
                           const float* __restrict__ bfp, const float* __restrict__ bip,
                           const float* __restrict__ bhp,
                           uint* __restrict__ Pav,
                           float* __restrict__ AggA, float* __restrict__ AggV)
{
  __shared__ ushort lds[2][4][BM * BK];   // [buf][A,Bf,Bi,Bh]  2 x 64 KiB = 128 KiB

  // bijective XCD swizzle, 1024 blocks
  const int id  = blockIdx.x;
  const int sw  = (id & 7) * 128 + (id >> 3);
  const int n0  = (sw & 7) * BN;
  const int m0  = (sw >> 3) * BM;

  const int tid  = threadIdx.x;
  const int lane = tid & 63;
  const int w    = tid >> 6;          // 0..7
  const int wr   = w >> 2;            // 0..1 : 64-row strip (== one scan chunk)
  const int wc   = w & 3;             // 0..3 : 32-col strip
  const int fr   = lane & 15, g = lane >> 4;

  // ---- swizzled ds_read offsets (halfwords): 16B slot (ks*4+g) ^ (row&7) ----
  int aoffh[4][2], boffh[2][2];
#pragma unroll
  for (int q = 0; q < 4; ++q)
#pragma unroll
    for (int ks = 0; ks < 2; ++ks) {
      int row = wr * 64 + q * 16 + fr;
      aoffh[q][ks] = row * BK + (((ks * 4 + g) ^ (row & 7)) << 3);
    }
#pragma unroll
  for (int n = 0; n < 2; ++n)
#pragma unroll
    for (int ks = 0; ks < 2; ++ks) {
      int row = wc * 32 + n * 16 + fr;
      boffh[n][ks] = row * BK + (((ks * 4 + g) ^ (row & 7)) << 3);
    }

  // ---- staging map: slots s0=tid, s1=512+tid; inverse-swizzled source column ----
  const int s0 = tid, s1 = 512 + tid;
  const int r0 = s0 >> 3, k0 = (s0 & 7) ^ (r0 & 7);
  const int r1 = s1 >> 3, k1 = (s1 & 7) ^ (r1 & 7);
  const int d0 = s0 * 8, d1 = s1 * 8;   // halfword dest offsets (linear)

  // A source: f32 x rows
  const float* pxA0 = Xf + (size_t)(m0 + r0) * K_DIM + k0 * 8;
  const float* pxA1 = Xf + (size_t)(m0 + r1) * K_DIM + k1 * 8;

  // B sources: bf16 W rows
  const ushort* gsrcB[3][2];
  gsrcB[0][0] = W0 + (size_t)(n0 + r0) * K_DIM + k0 * 8;
  gsrcB[0][1] = W0 + (size_t)(n0 + r1) * K_DIM + k1 * 8;
  gsrcB[1][0] = W1 + (size_t)(n0 + r0) * K_DIM + k0 * 8;
  gsrcB[1][1] = W1 + (size_t)(n0 + r1) * K_DIM + k1 * 8;
  gsrcB[2][0] = W2 + (size_t)(n0 + r0) * K_DIM + k0 * 8;
  gsrcB[2][1] = W2 + (size_t)(n0 + r1) * K_DIM + k1 * 8;

  auto issueB = [&](int buf, int zb, int kt, int j) {
    const ushort* s_ = gsrcB[zb][j] + kt * BK;
    __builtin_amdgcn_global_load_lds((const AS1 void*)s_,
        (AS3 void*)(&lds[buf][1 + zb][j ? d1 : d0]), 16, 0, 0);
  };

  // convert 16 f32 -> 16 bf16 and write both A slots of buffer `buf`
  auto writeA = [&](int buf, const float4& a0, const float4& a1,
                    const float4& a2, const float4& a3) {
    uint4 u0, u1;
    u0.x = cvtpk(a0.x, a0.y); u0.y = cvtpk(a0.z, a0.w);
    u0.z = cvtpk(a1.x, a1.y); u0.w = cvtpk(a1.z, a1.w);
    u1.x = cvtpk(a2.x, a2.y); u1.y = cvtpk(a2.z, a2.w);
    u1.z = cvtpk(a3.x, a3.y); u1.w = cvtpk(a3.z, a3.w);
    *reinterpret_cast<uint4*>(&lds[buf][0][d0]) = u0;
    *reinterpret_cast<uint4*>(&lds[buf][0][d1]) = u1;
  };

  f32x4 acc[3][4][2] = {};
  float4 fA0, fA1, fA2, fA3;

  // prologue: A f32 loads + B gloads for tile 0; drain; convert+write A; barrier
  fA0 = *reinterpret_cast<const float4*>(pxA0);
  fA1 = *reinterpret_cast<const float4*>(pxA0 + 4);
  fA2 = *reinterpret_cast<const float4*>(pxA1);
  fA3 = *reinterpret_cast<const float4*>(pxA1 + 4);
#pragma unroll
  for (int zb = 0; zb < 3; ++zb) { issueB(0, zb, 0, 0); issueB(0, zb, 0, 1); }
  WAITV0();
  writeA(0, fA0, fA1, fA2, fA3);
  WAITL0();
  BAR(); SB0();

  int cur = 0;
  for (int t = 0; t < NKT; ++t) {
    const bool pf = (t + 1 < NKT);
    const ushort* rb = &lds[cur][0][0];
    v8s aF[4][2], bA[2][2], bB[2][2];

    // ---- issue group 1: aF + bA<-B0 (12 ds_reads); then t+1 staging issues ----
#pragma unroll
    for (int q = 0; q < 4; ++q)
#pragma unroll
      for (int ks = 0; ks < 2; ++ks)
        aF[q][ks] = *reinterpret_cast<const v8s*>(rb + aoffh[q][ks]);
#pragma unroll
    for (int n = 0; n < 2; ++n)
#pragma unroll
      for (int ks = 0; ks < 2; ++ks)
        bA[n][ks] = *reinterpret_cast<const v8s*>(rb + 1 * BM * BK + boffh[n][ks]);
    SB0();
    if (pf) {
      const int ko = (t + 1) * BK;
      fA0 = *reinterpret_cast<const float4*>(pxA0 + ko);
      fA1 = *reinterpret_cast<const float4*>(pxA0 + ko + 4);
      fA2 = *reinterpret_cast<const float4*>(pxA1 + ko);
      fA3 = *reinterpret_cast<const float4*>(pxA1 + ko + 4);
#pragma unroll
      for (int zb = 0; zb < 3; ++zb) { issueB(cur ^ 1, zb, t + 1, 0); issueB(cur ^ 1, zb, t + 1, 1); }
    }
    SB0();
    // ---- issue group 2: bB<-B1 (4 ds_reads)  [lgkm outstanding: 16] ----
#pragma unroll
    for (int n = 0; n < 2; ++n)
#pragma unroll
      for (int ks = 0; ks < 2; ++ks)
        bB[n][ks] = *reinterpret_cast<const v8s*>(rb + 2 * BM * BK + boffh[n][ks]);
    SB0();
    WAITL4();   // aF + bA landed; bB in flight
    __builtin_amdgcn_s_setprio(1);
#pragma unroll
    for (int ks = 0; ks < 2; ++ks)
#pragma unroll
      for (int mi = 0; mi < 4; ++mi) {
        acc[0][mi][0] = __builtin_amdgcn_mfma_f32_16x16x32_bf16(aF[mi][ks], bA[0][ks], acc[0][mi][0], 0, 0, 0);
        acc[0][mi][1] = __builtin_amdgcn_mfma_f32_16x16x32_bf16(aF[mi][ks], bA[1][ks], acc[0][mi][1], 0, 0, 0);
      }
    __builtin_amdgcn_s_setprio(0);
    // ---- issue group 3: bA<-B2 (4 ds_reads)  [lgkm outstanding: 8] ----
#pragma unroll
    for (int n = 0; n < 2; ++n)
#pragma unroll
      for (int ks = 0; ks < 2; ++ks)
        bA[n][ks] = *reinterpret_cast<const v8s*>(rb + 3 * BM * BK + boffh[n][ks]);
    SB0();
    WAITL4();   // bB landed; bA(B2) in flight
    __builtin_amdgcn_s_setprio(1);
#pragma unroll
    for (int ks = 0; ks < 2; ++ks)
#pragma unroll
      for (int mi = 0; mi < 4; ++mi) {
        acc[1][mi][0] = __builtin_amdgcn_mfma_f32_16x16x32_bf16(aF[mi][ks], bB[0][ks], acc[1][mi][0], 0, 0, 0);
        acc[1][mi][1] = __builtin_amdgcn_mfma_f32_16x16x32_bf16(aF[mi][ks], bB[1][ks], acc[1][mi][1], 0, 0, 0);
      }
    __builtin_amdgcn_s_setprio(0);
    WAITL0();   // bA(B2) landed
    __builtin_amdgcn_s_setprio(1);
#pragma unroll
    for (int ks = 0; ks < 2; ++ks)
#pragma unroll
      for (int mi = 0; mi < 4; ++mi) {
        acc[2][mi][0] = __builtin_amdgcn_mfma_f32_16x16x32_bf16(aF[mi][ks], bA[0][ks], acc[2][mi][0], 0, 0, 0);
        acc[2][mi][1] = __builtin_amdgcn_mfma_f32_16x16x32_bf16(aF[mi][ks], bA[1][ks], acc[2][mi][1], 0, 0, 0);
      }
    __builtin_amdgcn_s_setprio(0);

    // ---- tile boundary: drain loads; convert+write A(t+1); publish; barrier ----
    if (pf) {
      WAITV0();                        // B gloads t+1 AND A f32 regs t+1 landed
      writeA(cur ^ 1, fA0, fA1, fA2, fA3);
      WAITL0();                        // ds_writes visible
      BAR(); SB0();
      cur ^= 1;
    }
  }

  // ---- epilogue: pack (a,v) AND build per-chunk scan aggregates ----
  const int bidx = m0 >> 12;                 // batch
  const int jch  = ((m0 & 4095) >> 6) + wr;  // per-batch chunk index of this strip
#pragma unroll
  for (int ni = 0; ni < 2; ++ni) {
    const int col = n0 + wc * 32 + ni * 16 + fr;
    const float vbf = bfp[col], vbi = bip[col], vbh = bhp[col];
    float BAgg[4], VAgg[4];
#pragma unroll
    for (int mi = 0; mi < 4; ++mi) {
      const int row0 = m0 + wr * 64 + mi * 16 + g * 4;
      float RA = 1.f, RV = 0.f;
#pragma unroll
      for (int r = 0; r < 4; ++r) {
        float a, v;
        gates(acc[0][mi][ni][r] + vbf, acc[1][mi][ni][r] + vbi, acc[2][mi][ni][r] + vbh, a, v);
        Pav[(size_t)(row0 + r) * N_DIM + col] = (uint)f2b(a) | ((uint)f2b(v) << 16);
        RA *= a; RV = fmaf(a, RV, v);
      }
      // ordered combine across g (runs at rows mi*16 + g*4): 2 xor rounds
      {
        float pA = __shfl_xor(RA, 16), pV = __shfl_xor(RV, 16);
        if (((lane >> 4) & 1) == 0) { RV = fmaf(pA, RV, pV); RA = RA * pA; }
        else                        { RV = fmaf(RA, pV, RV); RA = RA * pA; }
        pA = __shfl_xor(RA, 32); pV = __shfl_xor(RV, 32);
        if (((lane >> 5) & 1) == 0) { RV = fmaf(pA, RV, pV); RA = RA * pA; }
        else                        { RV = fmaf(RA, pV, RV); RA = RA * pA; }
      }
      BAgg[mi] = RA; VAgg[mi] = RV;
    }
    // ordered fold over mi (blocks of 16 rows)
    float CA = BAgg[0], CV = VAgg[0];
#pragma unroll
    for (int mi = 1; mi < 4; ++mi) { CV = fmaf(BAgg[mi], CV, VAgg[mi]); CA *= BAgg[mi]; }
    if (g == 0) {
      const int c = bidx * D_DIM + col;
      AggA[jch * NCHAN + c] = CA;
      AggV[jch * NCHAN + c] = CV;
    }
  }
}

// mid: sequential combine across chunk aggregates, 4 channels per thread
__global__ void scan_mid(const float4* __restrict__ AggA, const float4* __restrict__ AggV,
                         float4* __restrict__ Start)
{
  int c4 = blockIdx.x * blockDim.x + threadIdx.x;   // 1024
  float4 h = make_float4(0.f, 0.f, 0.f, 0.f);
#pragma unroll
  for (int j = 0; j < NCHUNK; ++j) {
    float4 A = AggA[(size_t)j * (NCHAN / 4) + c4];
    float4 V = AggV[(size_t)j * (NCHAN / 4) + c4];
    Start[(size_t)j * (NCHAN / 4) + c4] = h;
    h.x = fmaf(A.x, h.x, V.x);
    h.y = fmaf(A.y, h.y, V.y);
    h.z = fmaf(A.z, h.z, V.z);
    h.w = fmaf(A.w, h.w, V.w);
  }
}

// pass2: replay each chunk with true carry, 4 channels per thread, float4 out
__global__ void scan_pass2(const uint4* __restrict__ Pav4,
                           const float4* __restrict__ Start, float4* __restrict__ out4)
{
  int tid = blockIdx.x * blockDim.x + threadIdx.x;   // 65536
  int c4 = tid & 1023;
  int chunk = tid >> 10;
  int b = c4 >> 8;
  int d4 = c4 & 255;
  size_t base4 = ((size_t)b * L_SEQ + (size_t)chunk * CH) * (D_DIM / 4) + d4;
  float4 h = Start[(size_t)chunk * (NCHAN / 4) + c4];
#pragma unroll 4
  for (int t = 0; t < CH; ++t) {
    size_t idx = base4 + (size_t)t * (D_DIM / 4);
    uint4 u = Pav4[idx];
    h.x = fmaf(b2f((ushort)(u.x & 0xFFFFu)), h.x, b2f((ushort)(u.x >> 16)));
    h.y = fmaf(b2f((ushort)(u.y & 0xFFFFu)), h.y, b2f((ushort)(u.y >> 16)));
    h.z = fmaf(b2f((ushort)(u.z & 0xFFFFu)), h.z, b2f((ushort)(u.z >> 16)));
    h.w = fmaf(b2f((ushort)(u.w & 0xFFFFu)), h.w, b2f((ushort)(u.w >> 16)));
    out4[idx] = h;
  }
}

extern "C" void kernel_launch(void* const* d_in, const int* in_sizes, int n_in,
                              void* d_out, int out_size, void* d_ws, size_t ws_size,
                              hipStream_t stream) {
  (void)in_sizes; (void)n_in; (void)out_size; (void)ws_size;
  const float* x  = (const float*)d_in[0];
  const float* Wf = (const float*)d_in[1];
  const float* bf = (const float*)d_in[2];
  const float* Wi = (const float*)d_in[3];
  const float* bi = (const float*)d_in[4];
  const float* Wh = (const float*)d_in[5];
  const float* bh = (const float*)d_in[6];

  // workspace (~74 MB)
  ushort* wfb = (ushort*)d_ws;                         // 2 MB each
  ushort* wib = wfb + (size_t)N_DIM * K_DIM;
  ushort* whb = wib + (size_t)N_DIM * K_DIM;
  uint*  Pav  = (uint*)(whb + (size_t)N_DIM * K_DIM);  // 67 MB packed (a,v)
  float* AggA  = (float*)(Pav + (size_t)M_TOTAL * N_DIM);
  float* AggV  = AggA + NCHAN * NCHUNK;
  float* Start = AggV + NCHAN * NCHUNK;

  cast_w3<<<dim3((N_DIM * K_DIM / 4) / 256, 3), 256, 0, stream>>>(Wf, Wi, Wh, wfb, wib, whb);

  gemm_fused<<<dim3((M_TOTAL / BM) * (N_DIM / BN)), TPB, 0, stream>>>(
      x, wfb, wib, whb, bf, bi, bh, Pav, AggA, AggV);

  scan_mid<<<(NCHAN / 4) / 256, 256, 0, stream>>>(
      (const float4*)AggA, (const float4*)AggV, (float4*)Start);
  scan_pass2<<<(NCHAN / 4 * NCHUNK) / 256, 256, 0, stream>>>(
      (const uint4*)Pav, (const float4*)Start, (float4*)d_out);
}

// Round 15
// 161.332 us; speedup vs baseline: 1.3342x; 1.0176x over previous
//
#include <hip/hip_runtime.h>

// ---- problem geometry ----
#define M_TOTAL 16384          // B*L
#define N_DIM   1024           // D
#define K_DIM   1024
#define L_SEQ   4096
#define B_SZ    4
#define D_DIM   1024
#define CH      64             // scan chunk length (== wave row-strip)
#define NCHUNK  (L_SEQ / CH)   // 64
#define NCHAN   (B_SZ * D_DIM) // 4096

// ---- GEMM tile ----
#define BM 128
#define BN 128
#define BK 64
#define NKT (K_DIM / BK)       // 16
#define TPB 512                // 8 waves: 2M x 4N, wave tile 64x32

typedef __attribute__((ext_vector_type(8))) short v8s;
typedef __attribute__((ext_vector_type(4))) float f32x4;

#define SB0()   __builtin_amdgcn_sched_barrier(0)
#define BAR()   __builtin_amdgcn_s_barrier()
#define WAITL0() do { asm volatile("s_waitcnt lgkmcnt(0)" ::: "memory"); SB0(); } while (0)
#define WAITL4() do { asm volatile("s_waitcnt lgkmcnt(4)" ::: "memory"); SB0(); } while (0)
#define WAITV6() do { asm volatile("s_waitcnt vmcnt(6)"   ::: "memory"); SB0(); } while (0)
#define WAITV0() do { asm volatile("s_waitcnt vmcnt(0)"   ::: "memory"); SB0(); } while (0)
#define AS1 __attribute__((address_space(1)))
#define AS3 __attribute__((address_space(3)))

__device__ __forceinline__ ushort f2b(float f) {
  uint u = __float_as_uint(f);
  u += 0x7FFFu + ((u >> 16) & 1u);   // RNE (finite inputs)
  return (ushort)(u >> 16);
}
__device__ __forceinline__ float b2f(ushort u) {
  return __uint_as_float(((uint)u) << 16);
}
__device__ __forceinline__ uint cvtpk(float lo, float hi) {  // bf16(lo) | bf16(hi)<<16, HW RNE
  uint r;
  asm("v_cvt_pk_bf16_f32 %0, %1, %2" : "=v"(r) : "v"(lo), "v"(hi));
  return r;
}

__global__ void cast_w3(const float* __restrict__ s0, const float* __restrict__ s1,
                        const float* __restrict__ s2,
                        ushort* __restrict__ o0, ushort* __restrict__ o1, ushort* __restrict__ o2) {
  int i = blockIdx.x * blockDim.x + threadIdx.x;
  const float* s = (blockIdx.y == 0) ? s0 : (blockIdx.y == 1) ? s1 : s2;
  ushort* o      = (blockIdx.y == 0) ? o0 : (blockIdx.y == 1) ? o1 : o2;
  float4 v = reinterpret_cast<const float4*>(s)[i];
  ushort4 t = make_ushort4(f2b(v.x), f2b(v.y), f2b(v.z), f2b(v.w));
  reinterpret_cast<ushort4*>(o)[i] = t;
}

// gates: f = (1+e^-ip)/(2+e^-fp+e^-ip), i = 1-f, h~ = hp>=0 ? hp+0.5 : sigmoid(hp)
__device__ __forceinline__ void gates(float fp, float ip, float hp, float& a, float& v) {
  float Ef = __expf(-fp);
  float Ei = __expf(-ip);
  float r  = __builtin_amdgcn_rcpf(2.f + Ef + Ei);
  float f  = (1.f + Ei) * r;
  float i  = (1.f + Ef) * r;
  float ht = (hp >= 0.f) ? (hp + 0.5f) : __builtin_amdgcn_rcpf(1.f + __expf(-hp));
  a = f;
  v = i * ht;
}

// Fused 3-GEMM, cast-x fused into A-staging. A f32 loads issued FIRST in group 1
// (so vmcnt(6) at the z1->z2 seam retires exactly them); convert+ds_write happens
// there, under MFMA z2 cover; boundary is back to near-free waits + barrier.
__launch_bounds__(TPB, 2)
__global__ void gemm_fused(const float* __restrict__ Xf,
                           const ushort* __restrict__ W0, const ushort* __restrict__ W1,
                           const ushort* __restrict__ W2,
                           const float* __restrict__ bfp, const float* __restrict__ bip,
                           const float* __restrict__ bhp,
                           uint* __restrict__ Pav,
                           float* __restrict__ AggA, float* __restrict__ AggV)
{
  __shared__ ushort lds[2][4][BM * BK];   // [buf][A,Bf,Bi,Bh]  2 x 64 KiB = 128 KiB

  // bijective XCD swizzle, 1024 blocks
  const int id  = blockIdx.x;
  const int sw  = (id & 7) * 128 + (id >> 3);
  const int n0  = (sw & 7) * BN;
  const int m0  = (sw >> 3) * BM;

  const int tid  = threadIdx.x;
  const int lane = tid & 63;
  const int w    = tid >> 6;          // 0..7
  const int wr   = w >> 2;            // 0..1 : 64-row strip (== one scan chunk)
  const int wc   = w & 3;             // 0..3 : 32-col strip
  const int fr   = lane & 15, g = lane >> 4;

  // ---- swizzled ds_read offsets (halfwords): 16B slot (ks*4+g) ^ (row&7) ----
  int aoffh[4][2], boffh[2][2];
#pragma unroll
  for (int q = 0; q < 4; ++q)
#pragma unroll
    for (int ks = 0; ks < 2; ++ks) {
      int row = wr * 64 + q * 16 + fr;
      aoffh[q][ks] = row * BK + (((ks * 4 + g) ^ (row & 7)) << 3);
    }
#pragma unroll
  for (int n = 0; n < 2; ++n)
#pragma unroll
    for (int ks = 0; ks < 2; ++ks) {
      int row = wc * 32 + n * 16 + fr;
      boffh[n][ks] = row * BK + (((ks * 4 + g) ^ (row & 7)) << 3);
    }

  // ---- staging map: slots s0=tid, s1=512+tid; inverse-swizzled source column ----
  const int s0 = tid, s1 = 512 + tid;
  const int r0 = s0 >> 3, k0 = (s0 & 7) ^ (r0 & 7);
  const int r1 = s1 >> 3, k1 = (s1 & 7) ^ (r1 & 7);
  const int d0 = s0 * 8, d1 = s1 * 8;   // halfword dest offsets (linear)

  // A source: f32 x rows
  const float* pxA0 = Xf + (size_t)(m0 + r0) * K_DIM + k0 * 8;
  const float* pxA1 = Xf + (size_t)(m0 + r1) * K_DIM + k1 * 8;

  // B sources: bf16 W rows
  const ushort* gsrcB[3][2];
  gsrcB[0][0] = W0 + (size_t)(n0 + r0) * K_DIM + k0 * 8;
  gsrcB[0][1] = W0 + (size_t)(n0 + r1) * K_DIM + k1 * 8;
  gsrcB[1][0] = W1 + (size_t)(n0 + r0) * K_DIM + k0 * 8;
  gsrcB[1][1] = W1 + (size_t)(n0 + r1) * K_DIM + k1 * 8;
  gsrcB[2][0] = W2 + (size_t)(n0 + r0) * K_DIM + k0 * 8;
  gsrcB[2][1] = W2 + (size_t)(n0 + r1) * K_DIM + k1 * 8;

  auto issueB = [&](int buf, int zb, int kt, int j) {
    const ushort* s_ = gsrcB[zb][j] + kt * BK;
    __builtin_amdgcn_global_load_lds((const AS1 void*)s_,
        (AS3 void*)(&lds[buf][1 + zb][j ? d1 : d0]), 16, 0, 0);
  };

  // convert 16 f32 -> 16 bf16 and write both A slots of buffer `buf`
  auto writeA = [&](int buf, const float4& a0, const float4& a1,
                    const float4& a2, const float4& a3) {
    uint4 u0, u1;
    u0.x = cvtpk(a0.x, a0.y); u0.y = cvtpk(a0.z, a0.w);
    u0.z = cvtpk(a1.x, a1.y); u0.w = cvtpk(a1.z, a1.w);
    u1.x = cvtpk(a2.x, a2.y); u1.y = cvtpk(a2.z, a2.w);
    u1.z = cvtpk(a3.x, a3.y); u1.w = cvtpk(a3.z, a3.w);
    *reinterpret_cast<uint4*>(&lds[buf][0][d0]) = u0;
    *reinterpret_cast<uint4*>(&lds[buf][0][d1]) = u1;
  };

  f32x4 acc[3][4][2] = {};
  float4 fA0, fA1, fA2, fA3;

  // prologue: A f32 loads, then B gloads for tile 0; drain; write A; barrier
  fA0 = *reinterpret_cast<const float4*>(pxA0);
  fA1 = *reinterpret_cast<const float4*>(pxA0 + 4);
  fA2 = *reinterpret_cast<const float4*>(pxA1);
  fA3 = *reinterpret_cast<const float4*>(pxA1 + 4);
#pragma unroll
  for (int zb = 0; zb < 3; ++zb) { issueB(0, zb, 0, 0); issueB(0, zb, 0, 1); }
  WAITV0();
  writeA(0, fA0, fA1, fA2, fA3);
  WAITL0();
  BAR(); SB0();

  int cur = 0;
  for (int t = 0; t < NKT; ++t) {
    const bool pf = (t + 1 < NKT);
    const ushort* rb = &lds[cur][0][0];
    v8s aF[4][2], bA[2][2], bB[2][2];

    // ---- issue group 1: aF + bA<-B0 (12 ds_reads); A f32 loads FIRST, then B ----
#pragma unroll
    for (int q = 0; q < 4; ++q)
#pragma unroll
      for (int ks = 0; ks < 2; ++ks)
        aF[q][ks] = *reinterpret_cast<const v8s*>(rb + aoffh[q][ks]);
#pragma unroll
    for (int n = 0; n < 2; ++n)
#pragma unroll
      for (int ks = 0; ks < 2; ++ks)
        bA[n][ks] = *reinterpret_cast<const v8s*>(rb + 1 * BM * BK + boffh[n][ks]);
    SB0();
    if (pf) {
      const int ko = (t + 1) * BK;
      fA0 = *reinterpret_cast<const float4*>(pxA0 + ko);
      fA1 = *reinterpret_cast<const float4*>(pxA0 + ko + 4);
      fA2 = *reinterpret_cast<const float4*>(pxA1 + ko);
      fA3 = *reinterpret_cast<const float4*>(pxA1 + ko + 4);
      SB0();   // pin: A loads (4 vmcnt) issue before the 6 B gloads
#pragma unroll
      for (int zb = 0; zb < 3; ++zb) { issueB(cur ^ 1, zb, t + 1, 0); issueB(cur ^ 1, zb, t + 1, 1); }
    }
    SB0();
    // ---- issue group 2: bB<-B1 (4 ds_reads) ----
#pragma unroll
    for (int n = 0; n < 2; ++n)
#pragma unroll
      for (int ks = 0; ks < 2; ++ks)
        bB[n][ks] = *reinterpret_cast<const v8s*>(rb + 2 * BM * BK + boffh[n][ks]);
    SB0();
    WAITL4();   // aF + bA landed; bB in flight
    __builtin_amdgcn_s_setprio(1);
#pragma unroll
    for (int ks = 0; ks < 2; ++ks)
#pragma unroll
      for (int mi = 0; mi < 4; ++mi) {
        acc[0][mi][0] = __builtin_amdgcn_mfma_f32_16x16x32_bf16(aF[mi][ks], bA[0][ks], acc[0][mi][0], 0, 0, 0);
        acc[0][mi][1] = __builtin_amdgcn_mfma_f32_16x16x32_bf16(aF[mi][ks], bA[1][ks], acc[0][mi][1], 0, 0, 0);
      }
    __builtin_amdgcn_s_setprio(0);
    // ---- issue group 3: bA<-B2 (4 ds_reads) ----
#pragma unroll
    for (int n = 0; n < 2; ++n)
#pragma unroll
      for (int ks = 0; ks < 2; ++ks)
        bA[n][ks] = *reinterpret_cast<const v8s*>(rb + 3 * BM * BK + boffh[n][ks]);
    SB0();
    WAITL4();   // bB landed; bA(B2) in flight
    __builtin_amdgcn_s_setprio(1);
#pragma unroll
    for (int ks = 0; ks < 2; ++ks)
#pragma unroll
      for (int mi = 0; mi < 4; ++mi) {
        acc[1][mi][0] = __builtin_amdgcn_mfma_f32_16x16x32_bf16(aF[mi][ks], bB[0][ks], acc[1][mi][0], 0, 0, 0);
        acc[1][mi][1] = __builtin_amdgcn_mfma_f32_16x16x32_bf16(aF[mi][ks], bB[1][ks], acc[1][mi][1], 0, 0, 0);
      }
    __builtin_amdgcn_s_setprio(0);
    WAITL0();   // bA(B2) landed; lgkm queue now EMPTY
    // ---- z1->z2 seam: retire A f32 loads (vmcnt 6 = the 6 B gloads), write A ----
    if (pf) {
      WAITV6();
      writeA(cur ^ 1, fA0, fA1, fA2, fA3);   // 2 ds_writes retire under MFMA z2
      SB0();
    }
    __builtin_amdgcn_s_setprio(1);
#pragma unroll
    for (int ks = 0; ks < 2; ++ks)
#pragma unroll
      for (int mi = 0; mi < 4; ++mi) {
        acc[2][mi][0] = __builtin_amdgcn_mfma_f32_16x16x32_bf16(aF[mi][ks], bA[0][ks], acc[2][mi][0], 0, 0, 0);
        acc[2][mi][1] = __builtin_amdgcn_mfma_f32_16x16x32_bf16(aF[mi][ks], bA[1][ks], acc[2][mi][1], 0, 0, 0);
      }
    __builtin_amdgcn_s_setprio(0);

    // ---- tile boundary: near-free waits + barrier ----
    if (pf) {
      WAITV0();    // 6 B gloads (issued a full tile ago)
      WAITL0();    // 2 ds_writes (issued ~8 MFMA ago)
      BAR(); SB0();
      cur ^= 1;
    }
  }

  // ---- epilogue: pack (a,v) AND build per-chunk scan aggregates ----
  const int bidx = m0 >> 12;                 // batch
  const int jch  = ((m0 & 4095) >> 6) + wr;  // per-batch chunk index of this strip
#pragma unroll
  for (int ni = 0; ni < 2; ++ni) {
    const int col = n0 + wc * 32 + ni * 16 + fr;
    const float vbf = bfp[col], vbi = bip[col], vbh = bhp[col];
    float BAgg[4], VAgg[4];
#pragma unroll
    for (int mi = 0; mi < 4; ++mi) {
      const int row0 = m0 + wr * 64 + mi * 16 + g * 4;
      float RA = 1.f, RV = 0.f;
#pragma unroll
      for (int r = 0; r < 4; ++r) {
        float a, v;
        gates(acc[0][mi][ni][r] + vbf, acc[1][mi][ni][r] + vbi, acc[2][mi][ni][r] + vbh, a, v);
        Pav[(size_t)(row0 + r) * N_DIM + col] = (uint)f2b(a) | ((uint)f2b(v) << 16);
        RA *= a; RV = fmaf(a, RV, v);
      }
      // ordered combine across g (runs at rows mi*16 + g*4): 2 xor rounds
      {
        float pA = __shfl_xor(RA, 16), pV = __shfl_xor(RV, 16);
        if (((lane >> 4) & 1) == 0) { RV = fmaf(pA, RV, pV); RA = RA * pA; }
        else                        { RV = fmaf(RA, pV, RV); RA = RA * pA; }
        pA = __shfl_xor(RA, 32); pV = __shfl_xor(RV, 32);
        if (((lane >> 5) & 1) == 0) { RV = fmaf(pA, RV, pV); RA = RA * pA; }
        else                        { RV = fmaf(RA, pV, RV); RA = RA * pA; }
      }
      BAgg[mi] = RA; VAgg[mi] = RV;
    }
    // ordered fold over mi (blocks of 16 rows)
    float CA = BAgg[0], CV = VAgg[0];
#pragma unroll
    for (int mi = 1; mi < 4; ++mi) { CV = fmaf(BAgg[mi], CV, VAgg[mi]); CA *= BAgg[mi]; }
    if (g == 0) {
      const int c = bidx * D_DIM + col;
      AggA[jch * NCHAN + c] = CA;
      AggV[jch * NCHAN + c] = CV;
    }
  }
}

// mid: sequential combine across chunk aggregates, 4 channels per thread
__global__ void scan_mid(const float4* __restrict__ AggA, const float4* __restrict__ AggV,
                         float4* __restrict__ Start)
{
  int c4 = blockIdx.x * blockDim.x + threadIdx.x;   // 1024
  float4 h = make_float4(0.f, 0.f, 0.f, 0.f);
#pragma unroll
  for (int j = 0; j < NCHUNK; ++j) {
    float4 A = AggA[(size_t)j * (NCHAN / 4) + c4];
    float4 V = AggV[(size_t)j * (NCHAN / 4) + c4];
    Start[(size_t)j * (NCHAN / 4) + c4] = h;
    h.x = fmaf(A.x, h.x, V.x);
    h.y = fmaf(A.y, h.y, V.y);
    h.z = fmaf(A.z, h.z, V.z);
    h.w = fmaf(A.w, h.w, V.w);
  }
}

// pass2: replay each chunk with true carry, 4 channels per thread, float4 out
__global__ void scan_pass2(const uint4* __restrict__ Pav4,
                           const float4* __restrict__ Start, float4* __restrict__ out4)
{
  int tid = blockIdx.x * blockDim.x + threadIdx.x;   // 65536
  int c4 = tid & 1023;
  int chunk = tid >> 10;
  int b = c4 >> 8;
  int d4 = c4 & 255;
  size_t base4 = ((size_t)b * L_SEQ + (size_t)chunk * CH) * (D_DIM / 4) + d4;
  float4 h = Start[(size_t)chunk * (NCHAN / 4) + c4];
#pragma unroll 4
  for (int t = 0; t < CH; ++t) {
    size_t idx = base4 + (size_t)t * (D_DIM / 4);
    uint4 u = Pav4[idx];
    h.x = fmaf(b2f((ushort)(u.x & 0xFFFFu)), h.x, b2f((ushort)(u.x >> 16)));
    h.y = fmaf(b2f((ushort)(u.y & 0xFFFFu)), h.y, b2f((ushort)(u.y >> 16)));
    h.z = fmaf(b2f((ushort)(u.z & 0xFFFFu)), h.z, b2f((ushort)(u.z >> 16)));
    h.w = fmaf(b2f((ushort)(u.w & 0xFFFFu)), h.w, b2f((ushort)(u.w >> 16)));
    out4[idx] = h;
  }
}

extern "C" void kernel_launch(void* const* d_in, const int* in_sizes, int n_in,
                              void* d_out, int out_size, void* d_ws, size_t ws_size,
                              hipStream_t stream) {
  (void)in_sizes; (void)n_in; (void)out_size; (void)ws_size;
  const float* x  = (const float*)d_in[0];
  const float* Wf = (const float*)d_in[1];
  const float* bf = (const float*)d_in[2];
  const float* Wi = (const float*)d_in[3];
  const float* bi = (const float*)d_in[4];
  const float* Wh = (const float*)d_in[5];
  const float* bh = (const float*)d_in[6];

  // workspace (~74 MB)
  ushort* wfb = (ushort*)d_ws;                         // 2 MB each
  ushort* wib = wfb + (size_t)N_DIM * K_DIM;
  ushort* whb = wib + (size_t)N_DIM * K_DIM;
  uint*  Pav  = (uint*)(whb + (size_t)N_DIM * K_DIM);  // 67 MB packed (a,v)
  float* AggA  = (float*)(Pav + (size_t)M_TOTAL * N_DIM);
  float* AggV  = AggA + NCHAN * NCHUNK;
  float* Start = AggV + NCHAN * NCHUNK;

  cast_w3<<<dim3((N_DIM * K_DIM / 4) / 256, 3), 256, 0, stream>>>(Wf, Wi, Wh, wfb, wib, whb);

  gemm_fused<<<dim3((M_TOTAL / BM) * (N_DIM / BN)), TPB, 0, stream>>>(
      x, wfb, wib, whb, bf, bi, bh, Pav, AggA, AggV);

  scan_mid<<<(NCHAN / 4) / 256, 256, 0, stream>>>(
      (const float4*)AggA, (const float4*)AggV, (float4*)Start);
  scan_pass2<<<(NCHAN / 4 * NCHUNK) / 256, 256, 0, stream>>>(
      (const uint4*)Pav, (const float4*)Start, (float4*)d_out);
}